// Round 1
// baseline (57.324 us; speedup 1.0000x reference)
//
#include <hip/hip_runtime.h>

// PCEN: [1, F=1024, T=16384] fp32.
// EMA over time with S=0.5 decays as 0.5^k -> windowed recomputation with a
// 32-sample warmup window is exact to fp32 rounding.
//
// Each thread: one chunk of C=32 contiguous time samples of one freq row.
//   seed  = EMA over previous chunk [s-32, s) from m=0  (error <= 0.5^33)
//   main  = recurrence + pointwise PCEN, float4 I/O.

static constexpr int F = 1024;
static constexpr int T = 16384;
static constexpr int C = 32;          // chunk per thread (== warmup window)
static constexpr int CPR = T / C;     // 512 chunks per row
static constexpr float S_SMOOTH = 0.5f;
static constexpr float EPS = 1e-6f;

__global__ __launch_bounds__(256) void pcen_kernel(
    const float* __restrict__ data,
    const float* __restrict__ alpha_p,
    const float* __restrict__ r_p,
    const float* __restrict__ delta_p,
    float* __restrict__ out)
{
    const float alpha = alpha_p[0];
    const float r     = r_p[0];
    const float delta = delta_p[0];
    const float delta_r = exp2f(r * log2f(delta));   // delta ** r

    const int g = blockIdx.x * blockDim.x + threadIdx.x;
    if (g >= F * CPR) return;
    const int f = g >> 9;              // g / CPR   (CPR == 512)
    const int c = g & (CPR - 1);       // g % CPR
    const size_t base = (size_t)f * T + (size_t)c * C;

    // ---- seed: EMA over previous chunk starting from 0 ----
    float m = 0.0f;
    if (c != 0) {
        const float4* __restrict__ sv =
            reinterpret_cast<const float4*>(data + base - C);
        #pragma unroll
        for (int k = 0; k < C / 4; ++k) {
            float4 v = sv[k];
            m = S_SMOOTH * (m + v.x);   // mul-by-0.5 exact; one rounding/step
            m = S_SMOOTH * (m + v.y);
            m = S_SMOOTH * (m + v.z);
            m = S_SMOOTH * (m + v.w);
        }
    }

    // ---- main chunk ----
    const float4* __restrict__ xv = reinterpret_cast<const float4*>(data + base);
    float4*       __restrict__ ov = reinterpret_cast<float4*>(out + base);

    #pragma unroll
    for (int k = 0; k < C / 4; ++k) {
        float4 v = xv[k];
        float4 o;

        #define PCEN_ELEM(xx, oo)                                   \
        {                                                           \
            m = S_SMOOTH * (m + (xx));                              \
            float lg  = log2f(m + EPS);                             \
            float inv = exp2f(-alpha * lg);     /* (M+eps)^-alpha */\
            float q   = fmaf((xx), inv, delta);                     \
            oo = exp2f(r * log2f(q)) - delta_r;                     \
        }

        PCEN_ELEM(v.x, o.x);
        PCEN_ELEM(v.y, o.y);
        PCEN_ELEM(v.z, o.z);
        PCEN_ELEM(v.w, o.w);
        #undef PCEN_ELEM

        ov[k] = o;
    }
}

extern "C" void kernel_launch(void* const* d_in, const int* in_sizes, int n_in,
                              void* d_out, int out_size, void* d_ws, size_t ws_size,
                              hipStream_t stream) {
    const float* data  = (const float*)d_in[0];
    const float* alpha = (const float*)d_in[1];
    const float* r     = (const float*)d_in[2];
    const float* delta = (const float*)d_in[3];
    float* out = (float*)d_out;

    const int total_chunks = F * CPR;              // 524288 threads
    const int block = 256;
    const int grid = (total_chunks + block - 1) / block;   // 2048 blocks
    pcen_kernel<<<dim3(grid), dim3(block), 0, stream>>>(data, alpha, r, delta, out);
}

// Round 2
// 29.833 us; speedup vs baseline: 1.9215x; 1.9215x over previous
//
#include <hip/hip_runtime.h>

// PCEN [1, F=1024, T=16384] fp32.
// EMA with S=0.5 decays 2^-k  ->  32-sample warmup window is exact to fp32.
// R2: LDS-transposed I/O. All global traffic is lane-linear (coalesced);
// each thread's private 32-float window comes from LDS via an XOR swizzle
// (q ^ ((q>>3)&7)) that keeps every b128 LDS access bank-balanced.

static constexpr int F = 1024;
static constexpr int T = 16384;
static constexpr int C = 32;             // time chunk (= warmup window) per thread
static constexpr int BLOCK = 256;
static constexpr int HALF = BLOCK * C;   // 8192 floats per block (half a row)
static constexpr int SEEDQ = C / 4;      // 8 float4 of seed prefix
static constexpr int NQ = HALF / 4 + SEEDQ;  // 2056 float4 = 32.9 KB LDS
static constexpr float EPS = 1e-6f;

__device__ __forceinline__ int swz(int q) { return q ^ ((q >> 3) & 7); }

__device__ __forceinline__ void async_ld16(const float4* g, float4* l) {
  __builtin_amdgcn_global_load_lds(
      (const __attribute__((address_space(1))) void*)g,
      (__attribute__((address_space(3))) void*)l, 16, 0, 0);
}

__global__ __launch_bounds__(BLOCK) void pcen_kernel(
    const float* __restrict__ data,
    const float* __restrict__ alpha_p,
    const float* __restrict__ r_p,
    const float* __restrict__ delta_p,
    float* __restrict__ out)
{
  __shared__ float4 lds4[NQ];

  const int tid = threadIdx.x;
  const int bid = blockIdx.x;
  const int f = bid >> 1;                 // row
  const int h = bid & 1;                  // which half of the row
  const size_t base = (size_t)f * T + (size_t)h * HALF;
  const float4* __restrict__ g4 = reinterpret_cast<const float4*>(data + base);
  float4* __restrict__ o4 = reinterpret_cast<float4*>(out + base);

  // ---- stage global -> LDS: linear LDS dest, swizzle-inverse global src ----
  {
    const int wavebase = tid & ~63;       // wave-uniform LDS base (lane*16 added by HW)
    #pragma unroll
    for (int i = 0; i < 8; ++i) {
      const int p = SEEDQ + i * BLOCK + tid;          // linear LDS float4 pos
      async_ld16(g4 + (swz(p) - SEEDQ), &lds4[SEEDQ + i * BLOCK + wavebase]);
    }
    if (tid < SEEDQ) {
      if (h) {
        async_ld16(g4 - SEEDQ + tid, &lds4[0]);       // swz(q)==q for q<8
      } else {
        lds4[tid] = make_float4(0.f, 0.f, 0.f, 0.f);  // row start: EMA from 0
      }
    }
  }
  __syncthreads();   // drains vmcnt (global_load_lds) + lgkmcnt

  const float alpha = alpha_p[0];
  const float r     = r_p[0];
  const float delta = delta_p[0];
  const bool  rhalf = (r == 0.5f);
  const float delta_r = rhalf ? sqrtf(delta) : exp2f(r * log2f(delta));

  const int t8 = tid * 8;

  // ---- seed: EMA over previous 32 samples from m=0 (error <= 2^-33) ----
  float m = 0.0f;
  #pragma unroll
  for (int k = 0; k < 8; ++k) {
    float4 v = lds4[swz(t8 + k)];
    m = 0.5f * (m + v.x);
    m = 0.5f * (m + v.y);
    m = 0.5f * (m + v.z);
    m = 0.5f * (m + v.w);
  }

  // ---- main chunk: recurrence + pointwise PCEN into registers ----
  float4 res[8];

  #define PCEN_ELEM(XX, OO, POW)                        \
    { m = 0.5f * (m + (XX));                            \
      float lgm = log2f(m + EPS);                       \
      float inv = exp2f(-alpha * lgm);  /* (M+e)^-a */  \
      float qq  = fmaf((XX), inv, delta);               \
      OO = (POW) - delta_r; }

  if (rhalf) {
    #pragma unroll
    for (int k = 0; k < 8; ++k) {
      float4 v = lds4[swz(SEEDQ + t8 + k)];
      float4 o;
      PCEN_ELEM(v.x, o.x, sqrtf(qq));
      PCEN_ELEM(v.y, o.y, sqrtf(qq));
      PCEN_ELEM(v.z, o.z, sqrtf(qq));
      PCEN_ELEM(v.w, o.w, sqrtf(qq));
      res[k] = o;
    }
  } else {
    #pragma unroll
    for (int k = 0; k < 8; ++k) {
      float4 v = lds4[swz(SEEDQ + t8 + k)];
      float4 o;
      PCEN_ELEM(v.x, o.x, exp2f(r * log2f(qq)));
      PCEN_ELEM(v.y, o.y, exp2f(r * log2f(qq)));
      PCEN_ELEM(v.z, o.z, exp2f(r * log2f(qq)));
      PCEN_ELEM(v.w, o.w, exp2f(r * log2f(qq)));
      res[k] = o;
    }
  }
  #undef PCEN_ELEM

  // all reads of neighbor chunks must finish before overwriting in place
  __syncthreads();

  #pragma unroll
  for (int k = 0; k < 8; ++k) lds4[swz(SEEDQ + t8 + k)] = res[k];

  __syncthreads();

  // ---- LDS -> global, lane-linear stores (8 full cache lines / instr) ----
  #pragma unroll
  for (int i = 0; i < 8; ++i) {
    const int p = SEEDQ + i * BLOCK + tid;
    o4[p - SEEDQ] = lds4[swz(p)];   // lds4[swz(p)] holds element p
  }
}

extern "C" void kernel_launch(void* const* d_in, const int* in_sizes, int n_in,
                              void* d_out, int out_size, void* d_ws, size_t ws_size,
                              hipStream_t stream) {
  const float* data  = (const float*)d_in[0];
  const float* alpha = (const float*)d_in[1];
  const float* r     = (const float*)d_in[2];
  const float* delta = (const float*)d_in[3];
  float* out = (float*)d_out;

  const int grid = F * (T / HALF);   // 1024 * 2 = 2048 blocks
  pcen_kernel<<<dim3(grid), dim3(BLOCK), 0, stream>>>(data, alpha, r, delta, out);
}